// Round 2
// baseline (463.254 us; speedup 1.0000x reference)
//
#include <hip/hip_runtime.h>
#include <hip/hip_bf16.h>

// out = A @ W @ B, A/B block-diagonal with 128 blocks of 64x64.
// R4 = R3 resubmit (R3 bench died in infra: "container failed twice", no
// counters). Structure: persistent WG per (b, a-group of 8). B^T staged once
// and hoisted to registers; W/A loaded DIRECTLY into MFMA fragment layout
// from global (no LDS for W, A, or out); depth-1 prefetch of next tile's
// W/A; single barrier per tile (double-buffered tmp-transpose Tt only).
// Memory-bound target: ~0.54 GB total HBM traffic -> ~85 us floor.

#define D 8192
#define BS 64
#define GITER 8     // a-tiles per WG; grid = (128, 128/GITER)
#define LSTR 72     // bf16 LDS row stride (144 B: 16B-aligned, bank-staggered)

typedef __bf16  bf16x8 __attribute__((ext_vector_type(8)));
typedef float   f32x4  __attribute__((ext_vector_type(4)));

__device__ __forceinline__ unsigned short f2bf(float f) {
    union { float f; unsigned u; } v; v.f = f;
    unsigned r = v.u + 0x7FFFu + ((v.u >> 16) & 1u);
    return (unsigned short)(r >> 16);
}

__device__ __forceinline__ unsigned pkbf(float lo, float hi) {
    union { __hip_bfloat162 h; unsigned u; } c;
    c.h = __float22bfloat162_rn(make_float2(lo, hi));
    return c.u;
}

__device__ __forceinline__ bf16x8 mkfrag(f32x4 lo, f32x4 hi) {
    union { unsigned u[4]; bf16x8 v; } r;
    r.u[0] = pkbf(lo[0], lo[1]);
    r.u[1] = pkbf(lo[2], lo[3]);
    r.u[2] = pkbf(hi[0], hi[1]);
    r.u[3] = pkbf(hi[2], hi[3]);
    return r.v;
}

__global__ __launch_bounds__(256, 4) void bcl_kernel(
    const float* __restrict__ W,
    const float* __restrict__ Ab,
    const float* __restrict__ Bb,
    float* __restrict__ out)
{
    __shared__ __align__(16) unsigned short Bt[BS * LSTR];      // B_b^T [n][k], persistent
    __shared__ __align__(16) unsigned short Tt[2][BS * LSTR];   // tmp^T [n][m], double-buffered

    const int t  = threadIdx.x;
    const int b  = blockIdx.x;            // fixed column block
    const int a0 = blockIdx.y * GITER;    // first row block of this WG

    const int lane = t & 63;
    const int wv   = t >> 6;
    const int l16  = lane & 15;
    const int quad = lane >> 4;
    const int m0   = wv * 16;             // wave owns rows m0..m0+15 of each tile
    const int frow = m0 + l16;            // A-operand fragment row for this lane
    const int kq   = quad * 8;            // fragment k-offset (s-half adds 32)

    // Per-lane pointers in fragment layout (advance by one tile per iteration).
    const float* Wp = W   + (size_t)(a0 * BS + frow) * D + b * BS + kq;
    const float* Ap = Ab  + (size_t)a0 * BS * BS + frow * BS + kq;
    float*       Op = out + (size_t)(a0 * BS + m0 + quad * 4) * D + b * BS + l16;

    // ---- issue first tile's W/A loads immediately (longest latency) ----
    f32x4 w0 = __builtin_nontemporal_load((const f32x4*)(Wp + 0));
    f32x4 w1 = __builtin_nontemporal_load((const f32x4*)(Wp + 4));
    f32x4 w2 = __builtin_nontemporal_load((const f32x4*)(Wp + 32));
    f32x4 w3 = __builtin_nontemporal_load((const f32x4*)(Wp + 36));
    f32x4 av0 = *(const f32x4*)(Ap + 0);
    f32x4 av1 = *(const f32x4*)(Ap + 4);
    f32x4 av2 = *(const f32x4*)(Ap + 32);
    f32x4 av3 = *(const f32x4*)(Ap + 36);

    // ---- stage B^T once per WG (coalesced load, transposed bf16 writes) ----
    {
        const float* Bg = Bb + (size_t)b * BS * BS;
        const int r0 = t >> 4;
        const int c4 = (t & 15) << 2;
        #pragma unroll
        for (int i = 0; i < 4; ++i) {
            const int k = i * 16 + r0;
            f32x4 v = *(const f32x4*)(Bg + k * BS + c4);
            Bt[(c4 + 0) * LSTR + k] = f2bf(v[0]);
            Bt[(c4 + 1) * LSTR + k] = f2bf(v[1]);
            Bt[(c4 + 2) * LSTR + k] = f2bf(v[2]);
            Bt[(c4 + 3) * LSTR + k] = f2bf(v[3]);
        }
    }
    __syncthreads();

    // ---- hoist B^T fragments into registers (32 VGPRs), reused all GITER tiles ----
    bf16x8 btf[4][2];
    #pragma unroll
    for (int j = 0; j < 4; ++j) {
        btf[j][0] = *(const bf16x8*)&Bt[(j * 16 + l16) * LSTR + kq];
        btf[j][1] = *(const bf16x8*)&Bt[(j * 16 + l16) * LSTR + 32 + kq];
    }

    int buf = 0;
    #pragma unroll 1
    for (int i = 0; i < GITER; ++i) {
        // convert current tile's W/A into MFMA fragments
        bf16x8 waf0 = mkfrag(w0, w1);
        bf16x8 waf1 = mkfrag(w2, w3);
        bf16x8 aaf0 = mkfrag(av0, av1);
        bf16x8 aaf1 = mkfrag(av2, av3);

        // depth-1 prefetch: next tile's loads fly under mm1 + transpose + mm2
        if (i + 1 < GITER) {
            const float* Wn = Wp + (size_t)(i + 1) * BS * D;
            const float* An = Ap + (i + 1) * BS * BS;
            w0 = __builtin_nontemporal_load((const f32x4*)(Wn + 0));
            w1 = __builtin_nontemporal_load((const f32x4*)(Wn + 4));
            w2 = __builtin_nontemporal_load((const f32x4*)(Wn + 32));
            w3 = __builtin_nontemporal_load((const f32x4*)(Wn + 36));
            av0 = *(const f32x4*)(An + 0);
            av1 = *(const f32x4*)(An + 4);
            av2 = *(const f32x4*)(An + 32);
            av3 = *(const f32x4*)(An + 36);
        }

        // ---- mm1: tmp = W_ab @ B_b (both operands from registers) ----
        f32x4 acc1[4] = {};
        #pragma unroll
        for (int j = 0; j < 4; ++j)
            acc1[j] = __builtin_amdgcn_mfma_f32_16x16x32_bf16(waf0, btf[j][0], acc1[j], 0, 0, 0);
        #pragma unroll
        for (int j = 0; j < 4; ++j)
            acc1[j] = __builtin_amdgcn_mfma_f32_16x16x32_bf16(waf1, btf[j][1], acc1[j], 0, 0, 0);

        // ---- stage tmp^T (the one unavoidable cross-lane shuffle) ----
        unsigned short* Tb = Tt[buf];
        #pragma unroll
        for (int j = 0; j < 4; ++j) {
            uint2 p;
            p.x = pkbf(acc1[j][0], acc1[j][1]);
            p.y = pkbf(acc1[j][2], acc1[j][3]);
            *(uint2*)&Tb[(j * 16 + l16) * LSTR + m0 + quad * 4] = p;
        }
        __syncthreads();   // single barrier per tile (dbuf covers WAR hazard)

        // ---- mm2: out_ab = A_a @ tmp (A from registers, tmp from LDS) ----
        f32x4 acc2[4] = {};
        #pragma unroll
        for (int j = 0; j < 4; ++j) {
            bf16x8 tf = *(const bf16x8*)&Tb[(j * 16 + l16) * LSTR + kq];
            acc2[j] = __builtin_amdgcn_mfma_f32_16x16x32_bf16(aaf0, tf, acc2[j], 0, 0, 0);
        }
        #pragma unroll
        for (int j = 0; j < 4; ++j) {
            bf16x8 tf = *(const bf16x8*)&Tb[(j * 16 + l16) * LSTR + 32 + kq];
            acc2[j] = __builtin_amdgcn_mfma_f32_16x16x32_bf16(aaf1, tf, acc2[j], 0, 0, 0);
        }

        // ---- store straight from accumulators: each wave instr = 4x64B rows ----
        float* Or = Op + (size_t)i * BS * D;
        #pragma unroll
        for (int j = 0; j < 4; ++j) {
            #pragma unroll
            for (int r = 0; r < 4; ++r)
                __builtin_nontemporal_store(acc2[j][r], Or + (size_t)r * D + j * 16);
        }

        buf ^= 1;
    }
}

extern "C" void kernel_launch(void* const* d_in, const int* in_sizes, int n_in,
                              void* d_out, int out_size, void* d_ws, size_t ws_size,
                              hipStream_t stream) {
    const float* W = (const float*)d_in[0];
    const float* A = (const float*)d_in[1];
    const float* B = (const float*)d_in[2];
    float* o = (float*)d_out;
    dim3 grid(D / BS, D / BS / GITER);   // x = b (col block), y = a-group
    bcl_kernel<<<grid, 256, 0, stream>>>(W, A, B, o);
}

// Round 3
// 461.926 us; speedup vs baseline: 1.0029x; 1.0029x over previous
//
#include <hip/hip_runtime.h>
#include <hip/hip_bf16.h>

// out = A @ W @ B, A/B block-diagonal with 128 blocks of 64x64.
// R5 = R2 structure with ONE change: the per-tile __syncthreads() (which
// hipcc lowers with a full "s_waitcnt vmcnt(0)" drain, killing the cross-tile
// W/A prefetch) is replaced by an LDS-only drain + raw s_barrier:
//     s_waitcnt lgkmcnt(0); s_barrier;
// so prefetched global loads stay in flight across the barrier (T4, counted
// vmcnt discipline). Everything else (persistent WG per (b, 8 a-tiles), B^T
// register-resident, W/A fragment-direct loads, double-buffered tmp^T,
// accumulator-direct stores) is identical to the harness-verified R2.

#define D 8192
#define BS 64
#define GITER 8     // a-tiles per WG; grid = (128, 128/GITER)
#define LSTR 72     // bf16 LDS row stride (144 B: 16B-aligned, bank-staggered)

typedef __bf16  bf16x8 __attribute__((ext_vector_type(8)));
typedef float   f32x4  __attribute__((ext_vector_type(4)));

__device__ __forceinline__ unsigned short f2bf(float f) {
    union { float f; unsigned u; } v; v.f = f;
    unsigned r = v.u + 0x7FFFu + ((v.u >> 16) & 1u);
    return (unsigned short)(r >> 16);
}

__device__ __forceinline__ unsigned pkbf(float lo, float hi) {
    union { __hip_bfloat162 h; unsigned u; } c;
    c.h = __float22bfloat162_rn(make_float2(lo, hi));
    return c.u;
}

__device__ __forceinline__ bf16x8 mkfrag(f32x4 lo, f32x4 hi) {
    union { unsigned u[4]; bf16x8 v; } r;
    r.u[0] = pkbf(lo[0], lo[1]);
    r.u[1] = pkbf(lo[2], lo[3]);
    r.u[2] = pkbf(hi[0], hi[1]);
    r.u[3] = pkbf(hi[2], hi[3]);
    return r.v;
}

// LDS-visibility barrier that does NOT drain the vmem (global-load) queue.
// lgkmcnt(0): this wave's ds_writes are complete; s_barrier: all waves
// arrived; trailing memory clobber keeps the compiler from hoisting the
// subsequent ds_reads above the barrier.
__device__ __forceinline__ void lds_barrier() {
    asm volatile("s_waitcnt lgkmcnt(0)" ::: "memory");
    __builtin_amdgcn_s_barrier();
    asm volatile("" ::: "memory");
}

__global__ __launch_bounds__(256, 4) void bcl_kernel(
    const float* __restrict__ W,
    const float* __restrict__ Ab,
    const float* __restrict__ Bb,
    float* __restrict__ out)
{
    __shared__ __align__(16) unsigned short Bt[BS * LSTR];      // B_b^T [n][k], persistent
    __shared__ __align__(16) unsigned short Tt[2][BS * LSTR];   // tmp^T [n][m], double-buffered

    const int t  = threadIdx.x;
    const int b  = blockIdx.x;            // fixed column block
    const int a0 = blockIdx.y * GITER;    // first row block of this WG

    const int lane = t & 63;
    const int wv   = t >> 6;
    const int l16  = lane & 15;
    const int quad = lane >> 4;
    const int m0   = wv * 16;             // wave owns rows m0..m0+15 of each tile
    const int frow = m0 + l16;            // A-operand fragment row for this lane
    const int kq   = quad * 8;            // fragment k-offset (s-half adds 32)

    // Per-lane pointers in fragment layout (advance by one tile per iteration).
    const float* Wp = W   + (size_t)(a0 * BS + frow) * D + b * BS + kq;
    const float* Ap = Ab  + (size_t)a0 * BS * BS + frow * BS + kq;
    float*       Op = out + (size_t)(a0 * BS + m0 + quad * 4) * D + b * BS + l16;

    // ---- issue first tile's W/A loads immediately (longest latency) ----
    f32x4 w0 = __builtin_nontemporal_load((const f32x4*)(Wp + 0));
    f32x4 w1 = __builtin_nontemporal_load((const f32x4*)(Wp + 4));
    f32x4 w2 = __builtin_nontemporal_load((const f32x4*)(Wp + 32));
    f32x4 w3 = __builtin_nontemporal_load((const f32x4*)(Wp + 36));
    f32x4 av0 = *(const f32x4*)(Ap + 0);
    f32x4 av1 = *(const f32x4*)(Ap + 4);
    f32x4 av2 = *(const f32x4*)(Ap + 32);
    f32x4 av3 = *(const f32x4*)(Ap + 36);

    // ---- stage B^T once per WG (coalesced load, transposed bf16 writes) ----
    {
        const float* Bg = Bb + (size_t)b * BS * BS;
        const int r0 = t >> 4;
        const int c4 = (t & 15) << 2;
        #pragma unroll
        for (int i = 0; i < 4; ++i) {
            const int k = i * 16 + r0;
            f32x4 v = *(const f32x4*)(Bg + k * BS + c4);
            Bt[(c4 + 0) * LSTR + k] = f2bf(v[0]);
            Bt[(c4 + 1) * LSTR + k] = f2bf(v[1]);
            Bt[(c4 + 2) * LSTR + k] = f2bf(v[2]);
            Bt[(c4 + 3) * LSTR + k] = f2bf(v[3]);
        }
    }
    // One-time barrier; LDS-only drain so the W/A loads above stay in flight.
    lds_barrier();

    // ---- hoist B^T fragments into registers (32 VGPRs), reused all GITER tiles ----
    bf16x8 btf[4][2];
    #pragma unroll
    for (int j = 0; j < 4; ++j) {
        btf[j][0] = *(const bf16x8*)&Bt[(j * 16 + l16) * LSTR + kq];
        btf[j][1] = *(const bf16x8*)&Bt[(j * 16 + l16) * LSTR + 32 + kq];
    }

    int buf = 0;
    #pragma unroll 1
    for (int i = 0; i < GITER; ++i) {
        // convert current tile's W/A into MFMA fragments
        bf16x8 waf0 = mkfrag(w0, w1);
        bf16x8 waf1 = mkfrag(w2, w3);
        bf16x8 aaf0 = mkfrag(av0, av1);
        bf16x8 aaf1 = mkfrag(av2, av3);

        // depth-1 prefetch: now genuinely flies under mm1+transpose+mm2+store,
        // since no barrier below drains vmcnt.
        if (i + 1 < GITER) {
            const float* Wn = Wp + (size_t)(i + 1) * BS * D;
            const float* An = Ap + (i + 1) * BS * BS;
            w0 = __builtin_nontemporal_load((const f32x4*)(Wn + 0));
            w1 = __builtin_nontemporal_load((const f32x4*)(Wn + 4));
            w2 = __builtin_nontemporal_load((const f32x4*)(Wn + 32));
            w3 = __builtin_nontemporal_load((const f32x4*)(Wn + 36));
            av0 = *(const f32x4*)(An + 0);
            av1 = *(const f32x4*)(An + 4);
            av2 = *(const f32x4*)(An + 32);
            av3 = *(const f32x4*)(An + 36);
        }

        // ---- mm1: tmp = W_ab @ B_b (both operands from registers) ----
        f32x4 acc1[4] = {};
        #pragma unroll
        for (int j = 0; j < 4; ++j)
            acc1[j] = __builtin_amdgcn_mfma_f32_16x16x32_bf16(waf0, btf[j][0], acc1[j], 0, 0, 0);
        #pragma unroll
        for (int j = 0; j < 4; ++j)
            acc1[j] = __builtin_amdgcn_mfma_f32_16x16x32_bf16(waf1, btf[j][1], acc1[j], 0, 0, 0);

        // ---- stage tmp^T (the one unavoidable cross-lane shuffle) ----
        unsigned short* Tb = Tt[buf];
        #pragma unroll
        for (int j = 0; j < 4; ++j) {
            uint2 p;
            p.x = pkbf(acc1[j][0], acc1[j][1]);
            p.y = pkbf(acc1[j][2], acc1[j][3]);
            *(uint2*)&Tb[(j * 16 + l16) * LSTR + m0 + quad * 4] = p;
        }
        // single barrier per tile — LDS drain only, vmem prefetch survives
        lds_barrier();

        // ---- mm2: out_ab = A_a @ tmp (A from registers, tmp from LDS) ----
        f32x4 acc2[4] = {};
        #pragma unroll
        for (int j = 0; j < 4; ++j) {
            bf16x8 tf = *(const bf16x8*)&Tb[(j * 16 + l16) * LSTR + kq];
            acc2[j] = __builtin_amdgcn_mfma_f32_16x16x32_bf16(aaf0, tf, acc2[j], 0, 0, 0);
        }
        #pragma unroll
        for (int j = 0; j < 4; ++j) {
            bf16x8 tf = *(const bf16x8*)&Tb[(j * 16 + l16) * LSTR + 32 + kq];
            acc2[j] = __builtin_amdgcn_mfma_f32_16x16x32_bf16(aaf1, tf, acc2[j], 0, 0, 0);
        }

        // ---- store straight from accumulators: each wave instr = 4x64B rows ----
        float* Or = Op + (size_t)i * BS * D;
        #pragma unroll
        for (int j = 0; j < 4; ++j) {
            #pragma unroll
            for (int r = 0; r < 4; ++r)
                __builtin_nontemporal_store(acc2[j][r], Or + (size_t)r * D + j * 16);
        }

        buf ^= 1;
    }
}

extern "C" void kernel_launch(void* const* d_in, const int* in_sizes, int n_in,
                              void* d_out, int out_size, void* d_ws, size_t ws_size,
                              hipStream_t stream) {
    const float* W = (const float*)d_in[0];
    const float* A = (const float*)d_in[1];
    const float* B = (const float*)d_in[2];
    float* o = (float*)d_out;
    dim3 grid(D / BS, D / BS / GITER);   // x = b (col block), y = a-group
    bcl_kernel<<<grid, 256, 0, stream>>>(W, A, B, o);
}